// Round 3
// baseline (34242.706 us; speedup 1.0000x reference)
//
#include <hip/hip_runtime.h>
#include <stdint.h>

// Problem dims (fixed by the reference)
#define BSZ   1024
#define TT    8
#define DD    512
#define HH    512
#define NSEQ  (BSZ*TT)          // 8192 sequential steps per direction
#define FOURH (4*HH)            // 2048
#define POISON 0xAAAAAAAAu
#define G_ELEMS  ((size_t)2*NSEQ*FOURH)      // 33,554,432 floats (128 MB)
#define HB_ELEMS ((size_t)2*(NSEQ+1)*HH)     //  8,389,632 floats (32 MB)
#define POLL_CAP 4096           // hang-guard only

typedef __attribute__((ext_vector_type(4))) float vf4;

// Issue-only IC-coherent 32B load (NO wait — caller counts vmcnt).
__device__ __forceinline__ void poll_issue(const float* p, vf4& a, vf4& b){
  asm volatile("global_load_dwordx4 %0, %2, off sc0 sc1\n\t"
               "global_load_dwordx4 %1, %2, off offset:16 sc0 sc1"
               : "=v"(a), "=v"(b) : "v"(p) : "memory");
}
#define WAITVM(n)  asm volatile("s_waitcnt vmcnt(" #n ")" ::: "memory")
#define WAITLGKM() asm volatile("s_waitcnt lgkmcnt(0)" ::: "memory")
#define SB0()      __builtin_amdgcn_sched_barrier(0)

// IC-coherent 4B publish store.
__device__ __forceinline__ void st_ic(float* p, float v){
  asm volatile("global_store_dword %0, %1, off sc0 sc1"
               :: "v"(p), "v"(v) : "memory");
}

__device__ __forceinline__ bool valid8(const vf4& a, const vf4& b){
  return (__float_as_uint(a.x)!=POISON) & (__float_as_uint(a.y)!=POISON)
       & (__float_as_uint(a.z)!=POISON) & (__float_as_uint(a.w)!=POISON)
       & (__float_as_uint(b.x)!=POISON) & (__float_as_uint(b.y)!=POISON)
       & (__float_as_uint(b.z)!=POISON) & (__float_as_uint(b.w)!=POISON);
}

// ---------------------------------------------------------------------------
// Init: poison the h-pipeline buffer, seed slot 0 with h0.
// ---------------------------------------------------------------------------
__global__ void init_hbuf_k(float* __restrict__ hbuf, const float* __restrict__ h0)
{
  size_t idx = (size_t)blockIdx.x*blockDim.x + threadIdx.x;
  if (idx >= HB_ELEMS) return;
  int j = (int)(idx % HH);
  size_t r = idx / HH;
  int t   = (int)(r % (NSEQ+1));
  int dir = (int)(r / (NSEQ+1));
  uint32_t v;
  if (t == 0){
    uint32_t u = __float_as_uint(h0[dir*HH + j]);
    if (u == POISON) u ^= 1u;
    v = u;
  } else {
    v = POISON;
  }
  ((uint32_t*)hbuf)[idx] = v;
}

// ---------------------------------------------------------------------------
// Input-side GEMM: g[dir][n][m] = x[row]·W_ih_dir[m] + b_dir[m]
// ---------------------------------------------------------------------------
__global__ __launch_bounds__(256) void gemm_ih_k(
    const float* __restrict__ x,
    const float* __restrict__ Wf, const float* __restrict__ bf,
    const float* __restrict__ Wb, const float* __restrict__ bb,
    float* __restrict__ g)
{
  const int bm = blockIdx.x;
  const int bn = blockIdx.y;
  const int n0  = bm*64;
  const int m0g = bn*64;
  const int dir = m0g >> 11;
  const int m0  = m0g & 2047;
  const float* __restrict__ W    = dir ? Wb : Wf;
  const float* __restrict__ bias = dir ? bb : bf;

  __shared__ float As[32][68];
  __shared__ float Bs[32][68];

  const int tid = threadIdx.x;
  const int tx = tid & 15, ty = tid >> 4;
  float acc[4][4] = {};

  const int lr = tid >> 2;
  const int lk = (tid & 3) * 8;
  int arow = n0 + lr; if (dir) arow ^= 7;
  const float* ap = &x[(size_t)arow*DD];
  const float* wp = &W[(size_t)(m0+lr)*DD];

  for (int k0 = 0; k0 < DD; k0 += 32){
    float4 a0 = *(const float4*)&ap[k0+lk];
    float4 a1 = *(const float4*)&ap[k0+lk+4];
    float4 w0 = *(const float4*)&wp[k0+lk];
    float4 w1 = *(const float4*)&wp[k0+lk+4];
    __syncthreads();
    As[lk+0][lr]=a0.x; As[lk+1][lr]=a0.y; As[lk+2][lr]=a0.z; As[lk+3][lr]=a0.w;
    As[lk+4][lr]=a1.x; As[lk+5][lr]=a1.y; As[lk+6][lr]=a1.z; As[lk+7][lr]=a1.w;
    Bs[lk+0][lr]=w0.x; Bs[lk+1][lr]=w0.y; Bs[lk+2][lr]=w0.z; Bs[lk+3][lr]=w0.w;
    Bs[lk+4][lr]=w1.x; Bs[lk+5][lr]=w1.y; Bs[lk+6][lr]=w1.z; Bs[lk+7][lr]=w1.w;
    __syncthreads();
    #pragma unroll
    for (int kk = 0; kk < 32; kk++){
      float4 av = *(const float4*)&As[kk][ty*4];
      float4 bv = *(const float4*)&Bs[kk][tx*4];
      acc[0][0]+=av.x*bv.x; acc[0][1]+=av.x*bv.y; acc[0][2]+=av.x*bv.z; acc[0][3]+=av.x*bv.w;
      acc[1][0]+=av.y*bv.x; acc[1][1]+=av.y*bv.y; acc[1][2]+=av.y*bv.z; acc[1][3]+=av.y*bv.w;
      acc[2][0]+=av.z*bv.x; acc[2][1]+=av.z*bv.y; acc[2][2]+=av.z*bv.z; acc[2][3]+=av.z*bv.w;
      acc[3][0]+=av.w*bv.x; acc[3][1]+=av.w*bv.y; acc[3][2]+=av.w*bv.z; acc[3][3]+=av.w*bv.w;
    }
  }

  const size_t gbase = (size_t)dir*NSEQ*FOURH;
  #pragma unroll
  for (int i = 0; i < 4; i++){
    const int n = n0 + ty*4 + i;
    #pragma unroll
    for (int j = 0; j < 4; j++){
      const int m = m0 + tx*4 + j;
      g[gbase + (size_t)n*FOURH + m] = acc[i][j] + bias[m];
    }
  }
}

// ---------------------------------------------------------------------------
// Sequential bidirectional scan. 64 wgs (32/dir) x 1024 thr.
// One hidden unit per WAVE (16 units/wg): each 16-lane row computes one gate
// (32 MACs/lane), DPP rotate-reduce within 16, shfl-gather the 4 gate sums;
// gates computed wave-parallel; ONE raw barrier per step (double-buffered h
// LDS). Wave 0 polls h[t] with a depth-2 vmcnt-counted pipeline:
//   - polls for step t+1 are ISSUED at the end of body t (after the publish
//     stores), so store-ack and poll RTT overlap;
//   - loop-top WAITVM(2) = "all but 2 newest ops retired"; vmcnt retires
//     in-order (m135), so any older prefix (stores/leftover slots/weight
//     loads) only lengthens the wait — the validated slot is always retired;
//   - sched_barrier(0) after EVERY counted waitcnt (rule #18) so the
//     register-only poison check cannot be hoisted above the wait;
//   - poll regs are poison-initialized: any premature read fails safe.
// Wave 0's g values arrive via an LDS proxy written one step ahead by wave 1
// (no compiler-tracked global loads in wave 0's body -> no compiler vmcnt
// waits on its critical path).
// ---------------------------------------------------------------------------
#define DPP_ROR_ADD(v, ctrl) do { \
    int _t = __builtin_amdgcn_update_dpp(0, __float_as_int(v), (ctrl), 0xf, 0xf, false); \
    (v) += __int_as_float(_t); } while (0)

__global__ __launch_bounds__(1024, 4) void scan_k(
    const float* __restrict__ Whh_f, const float* __restrict__ Whh_b,
    const float* __restrict__ c0, const float* __restrict__ g,
    float* __restrict__ hbuf, float* __restrict__ out)
{
  const int bx  = blockIdx.x;
  const int dir = bx >> 5;
  const int w   = bx & 31;
  const int j0  = w << 4;
  const int tid  = threadIdx.x;
  const int lane = tid & 63;
  const int wv   = tid >> 6;          // wave id = unit within wg
  const int q    = lane >> 4;         // gate id (0..3): i,f,g,o row
  const int s    = lane & 15;         // k-slice id within gate row
  const int sx   = s & 7;             // LDS XOR key
  const int jmy  = j0 + wv;           // this wave's hidden unit

  const float* __restrict__ Whh = dir ? Whh_b : Whh_f;

  __shared__ vf4  hsh4[2][128];       // h[t] broadcast, double-buffered, XOR-swizzled
  __shared__ float gsh0[4][4];        // wave0's g proxy (4-slot rotation)
  volatile __shared__ int dead;

  // Recurrent weights: row (q*HH + jmy), cols [32s, 32s+32) -> 32 VGPRs.
  float wG[32];
  {
    const float* wp = &Whh[(size_t)(q*HH + jmy)*HH + (s<<5)];
    #pragma unroll
    for (int jj = 0; jj < 8; jj++){
      float4 v = ((const float4*)wp)[jj];
      wG[4*jj+0]=v.x; wG[4*jj+1]=v.y; wG[4*jj+2]=v.z; wG[4*jj+3]=v.w;
    }
  }

  float cst = c0[dir*HH + jmy];       // wave-uniform broadcast load

  float* __restrict__ hb = hbuf + (size_t)dir*(NSEQ+1)*HH;
  const float* __restrict__ gbp = g + (size_t)dir*NSEQ*FOURH;

  // g gate-input regs for step t (waves >= 1; wave 0 uses the LDS proxy).
  float pg0=0.f, pg1=0.f, pg2=0.f, pg3=0.f;
  if (wv != 0){
    const float* gp = &gbp[jmy];
    pg0 = gp[0]; pg1 = gp[HH]; pg2 = gp[2*HH]; pg3 = gp[3*HH];
  }
  if (wv == 1 && lane < 4) gsh0[0][lane] = gbp[lane*HH + j0];  // wave0's t=0 g
  if (tid == 0) dead = 0;
  __syncthreads();                    // full sync once (pre-loop)

  // Poll pipeline registers — POISON-init (fail-safe: premature reads re-poll).
  vf4 pA0, pB0, pA1, pB1;
  {
    const float pz = __uint_as_float(POISON);
    pA0 = (vf4){pz,pz,pz,pz}; pB0 = pA0; pA1 = pA0; pB1 = pA0;
  }

  // Prime the pipeline: issue both slots for h[0] (already valid from init).
  if (wv == 0){
    const float* hp0 = &hb[(size_t)(lane<<3)];
    poll_issue(hp0, pA0, pB0);
    poll_issue(hp0, pA1, pB1);
  }

  for (int t = 0; t < NSEQ; t++){
    // ---- wave 0: consume the in-flight depth-2 poll of h[t] ----
    if (wv == 0){
      const float* hp = &hb[(size_t)t*HH + (lane<<3)];
      vf4* dst = &hsh4[t & 1][0];
      const int c = lane << 1, xo = (c >> 3) & 7;
      bool got = false;
      for (int it = 0; it < POLL_CAP && !got; ++it){
        WAITVM(2); SB0();             // slot0 retired (in-order; prefix-robust)
        if (valid8(pA0, pB0)){
          dst[c ^ xo] = pA0; dst[(c+1) ^ xo] = pB0; got = true;
        } else {
          poll_issue(hp, pA0, pB0);
          WAITVM(2); SB0();           // slot1 retired
          if (valid8(pA1, pB1)){
            dst[c ^ xo] = pA1; dst[(c+1) ^ xo] = pB1; got = true;
          } else {
            poll_issue(hp, pA1, pB1);
          }
        }
      }
      if (!got) dead = 1;             // hang-guard only
    }
    WAITLGKM(); SB0();
    __builtin_amdgcn_s_barrier(); SB0();
    if (dead) break;

    // ---- g prefetch for t+1 (waves >= 1; wave 1 also fetches wave 0's) ----
    float ng0=0.f, ng1=0.f, ng2=0.f, ng3=0.f;
    float n00=0.f, n01=0.f, n02=0.f, n03=0.f;
    if (wv >= 1 && t+1 < NSEQ){
      const float* gp = &gbp[(size_t)(t+1)*FOURH + ((wv==1) ? j0 : jmy)];
      if (wv == 1){
        n00 = gp[0]; n01 = gp[HH]; n02 = gp[2*HH]; n03 = gp[3*HH];
        ng0 = gp[1]; ng1 = gp[HH+1]; ng2 = gp[2*HH+1]; ng3 = gp[3*HH+1];
      } else {
        ng0 = gp[0]; ng1 = gp[HH]; ng2 = gp[2*HH]; ng3 = gp[3*HH];
      }
    }

    // ---- read this lane's 32-float h slice (logical chunks 8s..8s+7) ----
    // phys(c) = c ^ ((c>>3)&7): read addr 8s + (j^sx) yields logical chunk j.
    const vf4* hv4 = hsh4[t & 1];
    const int cb = s << 3;
    vf4 h0_ = hv4[cb + (0 ^ sx)];
    vf4 h1_ = hv4[cb + (1 ^ sx)];
    vf4 h2_ = hv4[cb + (2 ^ sx)];
    vf4 h3_ = hv4[cb + (3 ^ sx)];
    vf4 h4_ = hv4[cb + (4 ^ sx)];
    vf4 h5_ = hv4[cb + (5 ^ sx)];
    vf4 h6_ = hv4[cb + (6 ^ sx)];
    vf4 h7_ = hv4[cb + (7 ^ sx)];

    // ---- one gate-row dot: 32 MACs as 4 independent chains ----
    float a0=0.f, a1=0.f, a2=0.f, a3=0.f;
    a0+=wG[ 0]*h0_.x; a1+=wG[ 1]*h0_.y; a2+=wG[ 2]*h0_.z; a3+=wG[ 3]*h0_.w;
    a0+=wG[ 4]*h1_.x; a1+=wG[ 5]*h1_.y; a2+=wG[ 6]*h1_.z; a3+=wG[ 7]*h1_.w;
    a0+=wG[ 8]*h2_.x; a1+=wG[ 9]*h2_.y; a2+=wG[10]*h2_.z; a3+=wG[11]*h2_.w;
    a0+=wG[12]*h3_.x; a1+=wG[13]*h3_.y; a2+=wG[14]*h3_.z; a3+=wG[15]*h3_.w;
    a0+=wG[16]*h4_.x; a1+=wG[17]*h4_.y; a2+=wG[18]*h4_.z; a3+=wG[19]*h4_.w;
    a0+=wG[20]*h5_.x; a1+=wG[21]*h5_.y; a2+=wG[22]*h5_.z; a3+=wG[23]*h5_.w;
    a0+=wG[24]*h6_.x; a1+=wG[25]*h6_.y; a2+=wG[26]*h6_.z; a3+=wG[27]*h6_.w;
    a0+=wG[28]*h7_.x; a1+=wG[29]*h7_.y; a2+=wG[30]*h7_.z; a3+=wG[31]*h7_.w;
    float zacc = (a0 + a2) + (a1 + a3);

    // ---- reduce within each 16-lane gate row (rotate-reduce) ----
    DPP_ROR_ADD(zacc, 0x128); DPP_ROR_ADD(zacc, 0x124);
    DPP_ROR_ADD(zacc, 0x122); DPP_ROR_ADD(zacc, 0x121);

    // ---- gather the 4 gate sums (lanes 0/16/32/48 hold z_i/z_f/z_g/z_o) ----
    float zi = __shfl(zacc, 0);
    float zf = __shfl(zacc, 16);
    float zg = __shfl(zacc, 32);
    float zo = __shfl(zacc, 48);

    float gi, gf, gg, go;
    if (wv == 0){ gi = gsh0[t&3][0]; gf = gsh0[t&3][1];
                  gg = gsh0[t&3][2]; go = gsh0[t&3][3]; }
    else        { gi = pg0; gf = pg1; gg = pg2; go = pg3; }

    zi += gi; zf += gf; zg += gg; zo += go;
    float si = 1.f/(1.f + __expf(-zi));
    float sf = 1.f/(1.f + __expf(-zf));
    float so = 1.f/(1.f + __expf(-zo));
    float e2g = __expf(2.f*zg);
    float tg  = (e2g - 1.f)/(e2g + 1.f);
    cst = sf*cst + si*tg;
    float e2c = __expf(2.f*cst);
    float tc  = (e2c - 1.f)/(e2c + 1.f);
    float hv  = so*tc;
    uint32_t u = __float_as_uint(hv);
    if (u == POISON) hv = __uint_as_float(u ^ 1u);

    if (lane == 0){
      st_ic(&hb[(size_t)(t+1)*HH + jmy], hv);          // publish first
      const int n = dir ? (t ^ 7) : t;
      out[(size_t)n*(2*HH) + dir*HH + jmy] = hv;
      if (t == NSEQ-1){
        out[(size_t)NSEQ*2*HH + dir*HH + jmy] = hv;            // h_n
        out[(size_t)NSEQ*2*HH + 2*HH + dir*HH + jmy] = cst;    // c_n
      }
    }

    // ---- rotate g pipeline; wave 1 hands wave 0 its t+1 values via LDS ----
    if (wv == 1 && t+1 < NSEQ && lane < 4){
      gsh0[(t+1)&3][lane] = (lane==0) ? n00 : (lane==1) ? n01
                          : (lane==2) ? n02 : n03;
    }
    if (wv >= 1){ pg0 = ng0; pg1 = ng1; pg2 = ng2; pg3 = ng3; }

    // ---- wave 0: issue next step's polls NOW (after stores) — store-ack
    //      and poll RTT overlap; no vmcnt drain anywhere in the loop. ----
    if (wv == 0 && t < NSEQ-1){
      const float* hpn = &hb[(size_t)(t+1)*HH + (lane<<3)];
      poll_issue(hpn, pA0, pB0);
      __builtin_amdgcn_s_sleep(4);    // ~256cy stagger (< IC RTT, off critical path)
      poll_issue(hpn, pA1, pB1);
    }
  }
}

// ---------------------------------------------------------------------------
extern "C" void kernel_launch(void* const* d_in, const int* in_sizes, int n_in,
                              void* d_out, int out_size, void* d_ws, size_t ws_size,
                              hipStream_t stream)
{
  const float* x    = (const float*)d_in[0];
  const float* h0   = (const float*)d_in[1];
  const float* c0   = (const float*)d_in[2];
  const float* Wihf = (const float*)d_in[3];
  const float* Whhf = (const float*)d_in[4];
  const float* bf   = (const float*)d_in[5];
  const float* Wihb = (const float*)d_in[6];
  const float* Whhb = (const float*)d_in[7];
  const float* bb   = (const float*)d_in[8];
  float* out = (float*)d_out;
  float* ws  = (float*)d_ws;

  float* g    = ws;                 // [2][8192][2048] fp32
  float* hbuf = ws + G_ELEMS;       // [2][8193][512]  fp32

  {
    int total = (int)HB_ELEMS;
    int blocks = (total + 255) / 256;
    init_hbuf_k<<<blocks, 256, 0, stream>>>(hbuf, h0);
  }
  {
    dim3 grid(NSEQ/64, (2*FOURH)/64);   // (128, 64)
    gemm_ih_k<<<grid, 256, 0, stream>>>(x, Wihf, bf, Wihb, bb, g);
  }
  scan_k<<<64, 1024, 0, stream>>>(Whhf, Whhb, c0, g, hbuf, out);
}

// Round 4
// 14580.460 us; speedup vs baseline: 2.3485x; 2.3485x over previous
//
#include <hip/hip_runtime.h>
#include <stdint.h>

// Problem dims (fixed by the reference)
#define BSZ   1024
#define TT    8
#define DD    512
#define HH    512
#define NSEQ  (BSZ*TT)          // 8192 sequential steps per direction
#define FOURH (4*HH)            // 2048
#define POISON 0xAAAAAAAAu
#define G_ELEMS  ((size_t)2*NSEQ*FOURH)      // 33,554,432 floats (128 MB)
#define HB_ELEMS ((size_t)2*(NSEQ+1)*HH)     //  8,389,632 floats (32 MB)
#define POLL_CAP (1<<16)        // hang-guard on the IC loop
#define FAST_CAP 512            // ~70us of throttled L2 polls before sticky IC escalation

typedef __attribute__((ext_vector_type(4))) float vf4;

// IC-coherent 32B load (bypasses L1+L2) — fallback / cross-XCD path.
__device__ __forceinline__ void ld2x16_ic(const float* p, vf4& a, vf4& b){
  asm volatile("global_load_dwordx4 %0, %2, off sc0 sc1\n\t"
               "global_load_dwordx4 %1, %2, off offset:16 sc0 sc1\n\t"
               "s_waitcnt vmcnt(0)"
               : "=v"(a), "=v"(b) : "v"(p) : "memory");
}
// L2-scope 32B load (bypasses L1 only). Same-XCD producers' sc0 sc1
// write-throughs update the shared L2 en route to IC, so this observes them
// at L2 latency (~250cy). Empirically confirmed in round 1 (FETCH collapse
// 285->86MB with correctness intact). Cross-XCD it can serve a stale line
// forever -> FAST_CAP sticky escalation below.
__device__ __forceinline__ void ld2x16_l2(const float* p, vf4& a, vf4& b){
  asm volatile("global_load_dwordx4 %0, %2, off sc0\n\t"
               "global_load_dwordx4 %1, %2, off offset:16 sc0\n\t"
               "s_waitcnt vmcnt(0)"
               : "=v"(a), "=v"(b) : "v"(p) : "memory");
}
// IC-coherent 4B publish store (write-through; same-XCD sc0 pollers coherent).
__device__ __forceinline__ void st_ic(float* p, float v){
  asm volatile("global_store_dword %0, %1, off sc0 sc1"
               :: "v"(p), "v"(v) : "memory");
}

__device__ __forceinline__ bool valid8(const vf4& a, const vf4& b){
  return (__float_as_uint(a.x)!=POISON) & (__float_as_uint(a.y)!=POISON)
       & (__float_as_uint(a.z)!=POISON) & (__float_as_uint(a.w)!=POISON)
       & (__float_as_uint(b.x)!=POISON) & (__float_as_uint(b.y)!=POISON)
       & (__float_as_uint(b.z)!=POISON) & (__float_as_uint(b.w)!=POISON);
}

// ---------------------------------------------------------------------------
// Init: poison the h-pipeline buffer, seed slot 0 with h0 (LSB-flip if it
// happens to equal the poison bit pattern).
// ---------------------------------------------------------------------------
__global__ void init_hbuf_k(float* __restrict__ hbuf, const float* __restrict__ h0)
{
  size_t idx = (size_t)blockIdx.x*blockDim.x + threadIdx.x;
  if (idx >= HB_ELEMS) return;
  int j = (int)(idx % HH);
  size_t r = idx / HH;
  int t   = (int)(r % (NSEQ+1));
  int dir = (int)(r / (NSEQ+1));
  uint32_t v;
  if (t == 0){
    uint32_t u = __float_as_uint(h0[dir*HH + j]);
    if (u == POISON) u ^= 1u;
    v = u;
  } else {
    v = POISON;
  }
  ((uint32_t*)hbuf)[idx] = v;
}

// ---------------------------------------------------------------------------
// Input-side GEMM: g[dir][n][m] = x[row]·W_ih_dir[m] + b_dir[m]
//   dir 0: row = n ; dir 1: row = n^7  (per-sample time reversal, T=8)
// ---------------------------------------------------------------------------
__global__ __launch_bounds__(256) void gemm_ih_k(
    const float* __restrict__ x,
    const float* __restrict__ Wf, const float* __restrict__ bf,
    const float* __restrict__ Wb, const float* __restrict__ bb,
    float* __restrict__ g)
{
  const int bm = blockIdx.x;          // 128 row tiles
  const int bn = blockIdx.y;          // 64 col tiles over combined N=4096
  const int n0  = bm*64;
  const int m0g = bn*64;
  const int dir = m0g >> 11;          // /2048
  const int m0  = m0g & 2047;
  const float* __restrict__ W    = dir ? Wb : Wf;
  const float* __restrict__ bias = dir ? bb : bf;

  __shared__ float As[32][68];
  __shared__ float Bs[32][68];

  const int tid = threadIdx.x;
  const int tx = tid & 15, ty = tid >> 4;
  float acc[4][4] = {};

  const int lr = tid >> 2;            // 0..63
  const int lk = (tid & 3) * 8;       // 0,8,16,24
  int arow = n0 + lr; if (dir) arow ^= 7;
  const float* ap = &x[(size_t)arow*DD];
  const float* wp = &W[(size_t)(m0+lr)*DD];

  for (int k0 = 0; k0 < DD; k0 += 32){
    float4 a0 = *(const float4*)&ap[k0+lk];
    float4 a1 = *(const float4*)&ap[k0+lk+4];
    float4 w0 = *(const float4*)&wp[k0+lk];
    float4 w1 = *(const float4*)&wp[k0+lk+4];
    __syncthreads();
    As[lk+0][lr]=a0.x; As[lk+1][lr]=a0.y; As[lk+2][lr]=a0.z; As[lk+3][lr]=a0.w;
    As[lk+4][lr]=a1.x; As[lk+5][lr]=a1.y; As[lk+6][lr]=a1.z; As[lk+7][lr]=a1.w;
    Bs[lk+0][lr]=w0.x; Bs[lk+1][lr]=w0.y; Bs[lk+2][lr]=w0.z; Bs[lk+3][lr]=w0.w;
    Bs[lk+4][lr]=w1.x; Bs[lk+5][lr]=w1.y; Bs[lk+6][lr]=w1.z; Bs[lk+7][lr]=w1.w;
    __syncthreads();
    #pragma unroll
    for (int kk = 0; kk < 32; kk++){
      float4 av = *(const float4*)&As[kk][ty*4];
      float4 bv = *(const float4*)&Bs[kk][tx*4];
      acc[0][0]+=av.x*bv.x; acc[0][1]+=av.x*bv.y; acc[0][2]+=av.x*bv.z; acc[0][3]+=av.x*bv.w;
      acc[1][0]+=av.y*bv.x; acc[1][1]+=av.y*bv.y; acc[1][2]+=av.y*bv.z; acc[1][3]+=av.y*bv.w;
      acc[2][0]+=av.z*bv.x; acc[2][1]+=av.z*bv.y; acc[2][2]+=av.z*bv.z; acc[2][3]+=av.z*bv.w;
      acc[3][0]+=av.w*bv.x; acc[3][1]+=av.w*bv.y; acc[3][2]+=av.w*bv.z; acc[3][3]+=av.w*bv.w;
    }
  }

  const size_t gbase = (size_t)dir*NSEQ*FOURH;
  #pragma unroll
  for (int i = 0; i < 4; i++){
    const int n = n0 + ty*4 + i;
    #pragma unroll
    for (int j = 0; j < 4; j++){
      const int m = m0 + tx*4 + j;
      g[gbase + (size_t)n*FOURH + m] = acc[i][j] + bias[m];
    }
  }
}

// ---------------------------------------------------------------------------
// Sequential bidirectional scan — PROVEN round-0 structure (gloader/zbuf/
// 2-barrier/coalesced 16-lane publish) with exactly one change: sync scope.
// Launched with 256 wgs; only bx%8==0 (dir 0) and bx%8==1 (dir 1) are real
// (32 wgs each, 1 wg/CU), so with the round-robin blockIdx->XCD mapping each
// direction's communicating set lands on ONE XCD and syncs through its
// shared L2 (sc0 polls, throttled with s_sleep(1)) instead of the IC.
// Round-1 evidence: placement + L2 coherence path CONFIRMED (FETCH collapse);
// its regression was the unthrottled poll storm — fixed here by the sleep.
// Sticky per-lane IC escalation after FAST_CAP keeps correctness
// placement-independent (G16).
// ---------------------------------------------------------------------------
#define DPP_ROR_ADD(v, ctrl) do { \
    int _t = __builtin_amdgcn_update_dpp(0, __float_as_int(v), (ctrl), 0xf, 0xf, false); \
    (v) += __int_as_float(_t); } while (0)

__global__ __launch_bounds__(1024, 4) void scan_k(
    const float* __restrict__ Whh_f, const float* __restrict__ Whh_b,
    const float* __restrict__ c0, const float* __restrict__ g,
    float* __restrict__ hbuf, float* __restrict__ out)
{
  const int bx  = blockIdx.x;
  const int sub = bx & 7;
  if (sub > 1) return;              // placement spacer wg: exit immediately
  const int dir = sub;              // dir 0 -> XCD0, dir 1 -> XCD1
  const int w   = bx >> 3;          // 0..31
  const int j0  = w << 4;
  const int tid  = threadIdx.x;
  const int lane = tid & 63;
  const int wv   = tid >> 6;
  const int s    = lane & 31;
  const int rb   = lane >> 5;
  const int r0   = (wv << 2) + rb;
  const int r1   = r0 + 2;

  const float* __restrict__ Whh = dir ? Whh_b : Whh_f;

  __shared__ vf4  hsh4[128];        // h[t] broadcast, XOR-swizzled chunks
  __shared__ float zbuf[64];
  __shared__ float gsh[64];
  __shared__ int dead;

  // Preload recurrent weights into VGPRs: rows r0/r1, k-slice [16s, 16s+16)
  float wA[16], wB[16];
  {
    const int gA = r0 >> 4, hA = r0 & 15;
    const int gB = r1 >> 4, hB = r1 & 15;
    const float* pa = &Whh[(size_t)(gA*HH + j0 + hA)*HH + (s<<4)];
    const float* pb = &Whh[(size_t)(gB*HH + j0 + hB)*HH + (s<<4)];
    #pragma unroll
    for (int q = 0; q < 4; q++){
      float4 va = ((const float4*)pa)[q];
      wA[4*q+0]=va.x; wA[4*q+1]=va.y; wA[4*q+2]=va.z; wA[4*q+3]=va.w;
      float4 vb = ((const float4*)pb)[q];
      wB[4*q+0]=vb.x; wB[4*q+1]=vb.y; wB[4*q+2]=vb.z; wB[4*q+3]=vb.w;
    }
  }

  float cst = 0.f;
  if (tid < 16) cst = c0[dir*HH + j0 + tid];
  if (tid == 0) dead = 0;
  __syncthreads();

  float* __restrict__ hb = hbuf + (size_t)dir*(NSEQ+1)*HH;
  const float* __restrict__ gbp = g + (size_t)dir*NSEQ*FOURH;

  const bool gloader = (tid >= 64) && (tid < 80);
  const int  gl = tid - 64;

  bool slow_lane = false;           // sticky per-lane escalation to IC polls

  for (int t = 0; t < NSEQ; t++){
    // g prefetch on wave 1 (off the polling wave's critical path).
    float pgi=0.f, pgf=0.f, pgg=0.f, pgo=0.f;
    if (gloader){
      const float* gp = &gbp[(size_t)t*FOURH + j0 + gl];
      pgi = gp[0]; pgf = gp[HH]; pgg = gp[2*HH]; pgo = gp[3*HH];
    }

    // Wave 0: poll h[t] (8 floats/lane). Fast path: throttled L2-scope polls
    // (same-XCD producer write-throughs land in our shared L2). Escalate a
    // lane to IC polls permanently if its line goes stale (remote producer).
    if (wv == 0){
      const float* hp = &hb[(size_t)t*HH + (lane<<3)];
      vf4 a, b;
      bool need = true;
      if (!slow_lane){
        for (int it = 0; it < FAST_CAP; ++it){
          ld2x16_l2(hp, a, b);
          if (valid8(a, b)){ need = false; break; }
          __builtin_amdgcn_s_sleep(1);       // ~64cy: keep L2 un-hammered
        }
        if (need) slow_lane = true;          // stale L2 line: producer remote
      }
      if (need){
        int it = 0;
        for (;;){
          ld2x16_ic(hp, a, b);
          if (valid8(a, b)) break;
          if (++it > POLL_CAP){ dead = 1; break; }
          __builtin_amdgcn_s_sleep(1);
        }
      }
      // Swizzled LDS broadcast: logical chunk c -> phys c ^ ((c>>3)&3).
      const int c0i = lane << 1;                 // 2L
      const int xo  = (c0i >> 3) & 3;
      hsh4[c0i ^ xo]       = a;
      hsh4[(c0i + 1) ^ xo] = b;
    }
    __syncthreads();
    if (dead) break;

    // Read this lane's k-slice [16s,16s+16) from swizzled LDS.
    vf4 h4a, h4b, h4c, h4d;
    {
      const int cb = s << 2;
      h4a = hsh4[(cb+0) ^ (((cb+0)>>3)&3)];
      h4b = hsh4[(cb+1) ^ (((cb+1)>>3)&3)];
      h4c = hsh4[(cb+2) ^ (((cb+2)>>3)&3)];
      h4d = hsh4[(cb+3) ^ (((cb+3)>>3)&3)];
    }

    // Two 16-long dot products per lane (4 independent FMA chains).
    float a0=0.f, a1=0.f, b0=0.f, b1=0.f;
    a0 += wA[ 0]*h4a.x; a1 += wA[ 1]*h4a.y; a0 += wA[ 2]*h4a.z; a1 += wA[ 3]*h4a.w;
    a0 += wA[ 4]*h4b.x; a1 += wA[ 5]*h4b.y; a0 += wA[ 6]*h4b.z; a1 += wA[ 7]*h4b.w;
    a0 += wA[ 8]*h4c.x; a1 += wA[ 9]*h4c.y; a0 += wA[10]*h4c.z; a1 += wA[11]*h4c.w;
    a0 += wA[12]*h4d.x; a1 += wA[13]*h4d.y; a0 += wA[14]*h4d.z; a1 += wA[15]*h4d.w;
    b0 += wB[ 0]*h4a.x; b1 += wB[ 1]*h4a.y; b0 += wB[ 2]*h4a.z; b1 += wB[ 3]*h4a.w;
    b0 += wB[ 4]*h4b.x; b1 += wB[ 5]*h4b.y; b0 += wB[ 6]*h4b.z; b1 += wB[ 7]*h4b.w;
    b0 += wB[ 8]*h4c.x; b1 += wB[ 9]*h4c.y; b0 += wB[10]*h4c.z; b1 += wB[11]*h4c.w;
    b0 += wB[12]*h4d.x; b1 += wB[13]*h4d.y; b0 += wB[14]*h4d.z; b1 += wB[15]*h4d.w;
    float accA = a0 + a1, accB = b0 + b1;

    // Reduce across 32 k-slices: 4 DPP row-rotates (within 16) + xor-16 swizzle.
    DPP_ROR_ADD(accA, 0x128); DPP_ROR_ADD(accA, 0x124);
    DPP_ROR_ADD(accA, 0x122); DPP_ROR_ADD(accA, 0x121);
    accA += __int_as_float(__builtin_amdgcn_ds_swizzle(__float_as_int(accA), 0x401F));
    DPP_ROR_ADD(accB, 0x128); DPP_ROR_ADD(accB, 0x124);
    DPP_ROR_ADD(accB, 0x122); DPP_ROR_ADD(accB, 0x121);
    accB += __int_as_float(__builtin_amdgcn_ds_swizzle(__float_as_int(accB), 0x401F));

    if (s == 0){ zbuf[r0] = accA; zbuf[r1] = accB; }
    if (gloader){ gsh[gl]=pgi; gsh[16+gl]=pgf; gsh[32+gl]=pgg; gsh[48+gl]=pgo; }
    __syncthreads();

    // Gate math + state update for this wg's 16 hidden units.
    if (tid < 16){
      float zi = zbuf[tid]      + gsh[tid];
      float zf = zbuf[16 + tid] + gsh[16 + tid];
      float zg = zbuf[32 + tid] + gsh[32 + tid];
      float zo = zbuf[48 + tid] + gsh[48 + tid];
      float si = 1.f/(1.f + __expf(-zi));
      float sf = 1.f/(1.f + __expf(-zf));
      float so = 1.f/(1.f + __expf(-zo));
      float e2g = __expf(2.f*zg);
      float tg  = (e2g - 1.f)/(e2g + 1.f);
      cst = sf*cst + si*tg;
      float e2c = __expf(2.f*cst);
      float tc  = (e2c - 1.f)/(e2c + 1.f);
      float hv  = so*tc;
      uint32_t u = __float_as_uint(hv);
      if (u == POISON) hv = __uint_as_float(u ^ 1u);   // keep poison unambiguous

      st_ic(&hb[(size_t)(t+1)*HH + j0 + tid], hv);     // publish first (16-lane coalesced)

      const int n = dir ? (t ^ 7) : t;                 // undo per-sample reversal
      out[(size_t)n*(2*HH) + dir*HH + j0 + tid] = hv;

      if (t == NSEQ-1){
        out[(size_t)NSEQ*2*HH + dir*HH + j0 + tid] = hv;          // h_n
        out[(size_t)NSEQ*2*HH + 2*HH + dir*HH + j0 + tid] = cst;  // c_n
      }
    }
    // No trailing barrier: next-step hsh4/zbuf writes are gated behind the
    // barrier following wave 0's poll of h[t+1], which requires these gate
    // threads (in wave 0) to have finished publishing.
  }
}

// ---------------------------------------------------------------------------
extern "C" void kernel_launch(void* const* d_in, const int* in_sizes, int n_in,
                              void* d_out, int out_size, void* d_ws, size_t ws_size,
                              hipStream_t stream)
{
  const float* x    = (const float*)d_in[0];
  const float* h0   = (const float*)d_in[1];
  const float* c0   = (const float*)d_in[2];
  const float* Wihf = (const float*)d_in[3];
  const float* Whhf = (const float*)d_in[4];
  const float* bf   = (const float*)d_in[5];
  const float* Wihb = (const float*)d_in[6];
  const float* Whhb = (const float*)d_in[7];
  const float* bb   = (const float*)d_in[8];
  float* out = (float*)d_out;
  float* ws  = (float*)d_ws;

  float* g    = ws;                 // [2][8192][2048] fp32
  float* hbuf = ws + G_ELEMS;       // [2][8193][512]  fp32

  {
    int total = (int)HB_ELEMS;
    int blocks = (total + 255) / 256;
    init_hbuf_k<<<blocks, 256, 0, stream>>>(hbuf, h0);
  }
  {
    dim3 grid(NSEQ/64, (2*FOURH)/64);   // (128, 64)
    gemm_ih_k<<<grid, 256, 0, stream>>>(x, Wihf, bf, Wihb, bb, g);
  }
  // 256 wgs: bx%8 in {0,1} are the 64 real wgs (32/dir), rest are spacers so
  // each direction's communicating set maps onto a single XCD (round-robin).
  scan_k<<<256, 1024, 0, stream>>>(Whhf, Whhb, c0, g, hbuf, out);
}

// Round 6
// 14233.102 us; speedup vs baseline: 2.4058x; 1.0244x over previous
//
#include <hip/hip_runtime.h>
#include <stdint.h>

// Problem dims (fixed by the reference)
#define BSZ   1024
#define TT    8
#define DD    512
#define HH    512
#define NSEQ  (BSZ*TT)          // 8192 sequential steps per direction
#define FOURH (4*HH)            // 2048
#define POISON 0xAAAAAAAAu
#define G_ELEMS  ((size_t)2*NSEQ*FOURH)      // 33,554,432 floats (128 MB)
#define HB_ELEMS ((size_t)2*(NSEQ+1)*HH)     //  8,389,632 floats (32 MB)
#define POLL_CAP 16384          // hang-guard

typedef __attribute__((ext_vector_type(4))) float vf4;

// Issue-only IC-coherent 32B load (NO wait — caller counts vmcnt).
__device__ __forceinline__ void poll_issue(const float* p, vf4& a, vf4& b){
  asm volatile("global_load_dwordx4 %0, %2, off sc0 sc1\n\t"
               "global_load_dwordx4 %1, %2, off offset:16 sc0 sc1"
               : "=v"(a), "=v"(b) : "v"(p) : "memory");
}
#define WAITVM(n)  asm volatile("s_waitcnt vmcnt(" #n ")" ::: "memory")
#define WAITLGKM() asm volatile("s_waitcnt lgkmcnt(0)" ::: "memory")
#define SB0()      __builtin_amdgcn_sched_barrier(0)

// IC-coherent 4B publish store.
__device__ __forceinline__ void st_ic(float* p, float v){
  asm volatile("global_store_dword %0, %1, off sc0 sc1"
               :: "v"(p), "v"(v) : "memory");
}

__device__ __forceinline__ bool valid8(const vf4& a, const vf4& b){
  return (__float_as_uint(a.x)!=POISON) & (__float_as_uint(a.y)!=POISON)
       & (__float_as_uint(a.z)!=POISON) & (__float_as_uint(a.w)!=POISON)
       & (__float_as_uint(b.x)!=POISON) & (__float_as_uint(b.y)!=POISON)
       & (__float_as_uint(b.z)!=POISON) & (__float_as_uint(b.w)!=POISON);
}

// ---------------------------------------------------------------------------
// Init: poison the h-pipeline buffer, seed slot 0 with h0 (LSB-flip if it
// happens to equal the poison bit pattern).
// ---------------------------------------------------------------------------
__global__ void init_hbuf_k(float* __restrict__ hbuf, const float* __restrict__ h0)
{
  size_t idx = (size_t)blockIdx.x*blockDim.x + threadIdx.x;
  if (idx >= HB_ELEMS) return;
  int j = (int)(idx % HH);
  size_t r = idx / HH;
  int t   = (int)(r % (NSEQ+1));
  int dir = (int)(r / (NSEQ+1));
  uint32_t v;
  if (t == 0){
    uint32_t u = __float_as_uint(h0[dir*HH + j]);
    if (u == POISON) u ^= 1u;
    v = u;
  } else {
    v = POISON;
  }
  ((uint32_t*)hbuf)[idx] = v;
}

// ---------------------------------------------------------------------------
// Input-side GEMM: g[dir][n][m] = x[row]·W_ih_dir[m] + b_dir[m]
//   dir 0: row = n ; dir 1: row = n^7  (per-sample time reversal, T=8)
// ---------------------------------------------------------------------------
__global__ __launch_bounds__(256) void gemm_ih_k(
    const float* __restrict__ x,
    const float* __restrict__ Wf, const float* __restrict__ bf,
    const float* __restrict__ Wb, const float* __restrict__ bb,
    float* __restrict__ g)
{
  const int bm = blockIdx.x;          // 128 row tiles
  const int bn = blockIdx.y;          // 64 col tiles over combined N=4096
  const int n0  = bm*64;
  const int m0g = bn*64;
  const int dir = m0g >> 11;          // /2048
  const int m0  = m0g & 2047;
  const float* __restrict__ W    = dir ? Wb : Wf;
  const float* __restrict__ bias = dir ? bb : bf;

  __shared__ float As[32][68];
  __shared__ float Bs[32][68];

  const int tid = threadIdx.x;
  const int tx = tid & 15, ty = tid >> 4;
  float acc[4][4] = {};

  const int lr = tid >> 2;            // 0..63
  const int lk = (tid & 3) * 8;       // 0,8,16,24
  int arow = n0 + lr; if (dir) arow ^= 7;
  const float* ap = &x[(size_t)arow*DD];
  const float* wp = &W[(size_t)(m0+lr)*DD];

  for (int k0 = 0; k0 < DD; k0 += 32){
    float4 a0 = *(const float4*)&ap[k0+lk];
    float4 a1 = *(const float4*)&ap[k0+lk+4];
    float4 w0 = *(const float4*)&wp[k0+lk];
    float4 w1 = *(const float4*)&wp[k0+lk+4];
    __syncthreads();
    As[lk+0][lr]=a0.x; As[lk+1][lr]=a0.y; As[lk+2][lr]=a0.z; As[lk+3][lr]=a0.w;
    As[lk+4][lr]=a1.x; As[lk+5][lr]=a1.y; As[lk+6][lr]=a1.z; As[lk+7][lr]=a1.w;
    Bs[lk+0][lr]=w0.x; Bs[lk+1][lr]=w0.y; Bs[lk+2][lr]=w0.z; Bs[lk+3][lr]=w0.w;
    Bs[lk+4][lr]=w1.x; Bs[lk+5][lr]=w1.y; Bs[lk+6][lr]=w1.z; Bs[lk+7][lr]=w1.w;
    __syncthreads();
    #pragma unroll
    for (int kk = 0; kk < 32; kk++){
      float4 av = *(const float4*)&As[kk][ty*4];
      float4 bv = *(const float4*)&Bs[kk][tx*4];
      acc[0][0]+=av.x*bv.x; acc[0][1]+=av.x*bv.y; acc[0][2]+=av.x*bv.z; acc[0][3]+=av.x*bv.w;
      acc[1][0]+=av.y*bv.x; acc[1][1]+=av.y*bv.y; acc[1][2]+=av.y*bv.z; acc[1][3]+=av.y*bv.w;
      acc[2][0]+=av.z*bv.x; acc[2][1]+=av.z*bv.y; acc[2][2]+=av.z*bv.z; acc[2][3]+=av.z*bv.w;
      acc[3][0]+=av.w*bv.x; acc[3][1]+=av.w*bv.y; acc[3][2]+=av.w*bv.z; acc[3][3]+=av.w*bv.w;
    }
  }

  const size_t gbase = (size_t)dir*NSEQ*FOURH;
  #pragma unroll
  for (int i = 0; i < 4; i++){
    const int n = n0 + ty*4 + i;
    #pragma unroll
    for (int j = 0; j < 4; j++){
      const int m = m0 + tx*4 + j;
      g[gbase + (size_t)n*FOURH + m] = acc[i][j] + bias[m];
    }
  }
}

// ---------------------------------------------------------------------------
// Sequential bidirectional scan — round-0 proven fabric (64 wgs, IC-scope
// value-carried sync, gloader/zbuf, coalesced 16-lane publish) with:
//  1. Strided column partition: lane k-slice s owns cols {128q+4s+j}, q,j=0..3.
//     Broadcast writes and slice reads are bank-dense -> ~zero LDS conflicts
//     (round-0 pattern measured 1.34e8 total = ~256cy/step).
//  2. Dual-slot vmcnt-counted IC poll — ROUND-3-PROVEN form restored exactly:
//     FUNCTION-SCOPE loop-carried poll regs (permanently live: in-flight
//     loads can never clobber reused registers — the round-5 bug), prime
//     before loop, consume at loop top (WAITVM(2)+sched_barrier(0) per rule
//     #18), reissue at end of body after the publish stores, NO drain (in-
//     order vmcnt retirement makes the "2 newest = other slot" invariant
//     hold across any prefix of stores/reissues; double-writes to the same
//     reg resolve in order to the newest value).
//     Raw lgkm-only barriers (not __syncthreads) so no vmcnt(0) drain ever
//     stalls wave 0's in-flight polls.
//  3. Publish-first ordering + v_rcp fast-math gates (absmax headroom 7x).
// ---------------------------------------------------------------------------
#define DPP_ROR_ADD(v, ctrl) do { \
    int _t = __builtin_amdgcn_update_dpp(0, __float_as_int(v), (ctrl), 0xf, 0xf, false); \
    (v) += __int_as_float(_t); } while (0)

__global__ __launch_bounds__(1024, 4) void scan_k(
    const float* __restrict__ Whh_f, const float* __restrict__ Whh_b,
    const float* __restrict__ c0, const float* __restrict__ g,
    float* __restrict__ hbuf, float* __restrict__ out)
{
  const int bx  = blockIdx.x;
  const int dir = bx >> 5;
  const int w   = bx & 31;
  const int j0  = w << 4;
  const int tid  = threadIdx.x;
  const int lane = tid & 63;
  const int wv   = tid >> 6;
  const int s    = lane & 31;         // k-slice id (32 slices x 16 cols)
  const int rb   = lane >> 5;
  const int r0   = (wv << 2) + rb;    // z-rows: wave wv covers rows 4wv..4wv+3
  const int r1   = r0 + 2;

  const float* __restrict__ Whh = dir ? Whh_b : Whh_f;

  __shared__ vf4  hsh4[128];          // h[t] broadcast, LINEAR chunks (strided partition)
  __shared__ float zbuf[64];
  __shared__ float gsh[64];
  volatile __shared__ int dead;

  // Recurrent weights for rows r0/r1 over this lane's strided column set:
  // wX[4q+j] = W[row][128q + 4s + j]  (matches h4{q}[j] below).
  float wA[16], wB[16];
  {
    const int gA = r0 >> 4, hA = r0 & 15;
    const int gB = r1 >> 4, hB = r1 & 15;
    const float* pa = &Whh[(size_t)(gA*HH + j0 + hA)*HH];
    const float* pb = &Whh[(size_t)(gB*HH + j0 + hB)*HH];
    #pragma unroll
    for (int q = 0; q < 4; q++){
      float4 va = *(const float4*)&pa[q*128 + (s<<2)];
      wA[4*q+0]=va.x; wA[4*q+1]=va.y; wA[4*q+2]=va.z; wA[4*q+3]=va.w;
      float4 vb = *(const float4*)&pb[q*128 + (s<<2)];
      wB[4*q+0]=vb.x; wB[4*q+1]=vb.y; wB[4*q+2]=vb.z; wB[4*q+3]=vb.w;
    }
  }

  float cst = 0.f;
  if (tid < 16) cst = c0[dir*HH + j0 + tid];
  if (tid == 0) dead = 0;
  __syncthreads();                    // one full sync pre-loop (drains everything)

  float* __restrict__ hb = hbuf + (size_t)dir*(NSEQ+1)*HH;
  const float* __restrict__ gbp = g + (size_t)dir*NSEQ*FOURH;

  const bool gloader = (tid >= 64) && (tid < 80);
  const int  gl = tid - 64;

  // Poll pipeline registers — FUNCTION SCOPE, loop-carried (round-3-proven):
  // allocator keeps them live for the whole kernel; in-flight loads are safe.
  vf4 pA0, pB0, pA1, pB1;
  {
    const float pz = __uint_as_float(POISON);
    pA0 = (vf4){pz,pz,pz,pz}; pB0 = pA0; pA1 = pA0; pB1 = pA0;
  }
  // Prime: issue both slots for h[0] (valid from init_hbuf_k).
  if (wv == 0){
    const float* hp0 = &hb[(size_t)(lane<<3)];
    poll_issue(hp0, pA0, pB0);
    poll_issue(hp0, pA1, pB1);
  }

  for (int t = 0; t < NSEQ; t++){
    // g prefetch on wave 1 (overlaps wave 0's poll).
    float pgi=0.f, pgf=0.f, pgg=0.f, pgo=0.f;
    if (gloader){
      const float* gp = &gbp[(size_t)t*FOURH + j0 + gl];
      pgi = gp[0]; pgf = gp[HH]; pgg = gp[2*HH]; pgo = gp[3*HH];
    }

    // ---- wave 0: consume the in-flight dual-slot poll of h[t] ----
    if (wv == 0){
      const float* hp = &hb[(size_t)t*HH + (lane<<3)];
      const int c = lane << 1;        // linear chunk index
      bool got = false;
      for (int it = 0; it < POLL_CAP && !got; ++it){
        WAITVM(2); SB0();             // newest-2 = slot1's pair -> slot0 retired
        if (valid8(pA0, pB0)){
          hsh4[c] = pA0; hsh4[c+1] = pB0; got = true;
        } else {
          poll_issue(hp, pA0, pB0);
          WAITVM(2); SB0();           // newest-2 = slot0' -> slot1 retired
          if (valid8(pA1, pB1)){
            hsh4[c] = pA1; hsh4[c+1] = pB1; got = true;
          } else {
            poll_issue(hp, pA1, pB1);
          }
        }
      }
      if (!got) dead = 1;             // hang-guard only
    }
    WAITLGKM(); SB0();
    __builtin_amdgcn_s_barrier(); SB0();   // raw barrier #1 (polls may be in flight)
    if (dead) break;

    // ---- read this lane's strided h slice: chunks {s, 32+s, 64+s, 96+s} ----
    vf4 h4a = hsh4[s];
    vf4 h4b = hsh4[32 + s];
    vf4 h4c = hsh4[64 + s];
    vf4 h4d = hsh4[96 + s];

    // ---- two 16-long dot products per lane (4 independent FMA chains) ----
    float a0=0.f, a1=0.f, b0=0.f, b1=0.f;
    a0 += wA[ 0]*h4a.x; a1 += wA[ 1]*h4a.y; a0 += wA[ 2]*h4a.z; a1 += wA[ 3]*h4a.w;
    a0 += wA[ 4]*h4b.x; a1 += wA[ 5]*h4b.y; a0 += wA[ 6]*h4b.z; a1 += wA[ 7]*h4b.w;
    a0 += wA[ 8]*h4c.x; a1 += wA[ 9]*h4c.y; a0 += wA[10]*h4c.z; a1 += wA[11]*h4c.w;
    a0 += wA[12]*h4d.x; a1 += wA[13]*h4d.y; a0 += wA[14]*h4d.z; a1 += wA[15]*h4d.w;
    b0 += wB[ 0]*h4a.x; b1 += wB[ 1]*h4a.y; b0 += wB[ 2]*h4a.z; b1 += wB[ 3]*h4a.w;
    b0 += wB[ 4]*h4b.x; b1 += wB[ 5]*h4b.y; b0 += wB[ 6]*h4b.z; b1 += wB[ 7]*h4b.w;
    b0 += wB[ 8]*h4c.x; b1 += wB[ 9]*h4c.y; b0 += wB[10]*h4c.z; b1 += wB[11]*h4c.w;
    b0 += wB[12]*h4d.x; b1 += wB[13]*h4d.y; b0 += wB[14]*h4d.z; b1 += wB[15]*h4d.w;
    float accA = a0 + a1, accB = b0 + b1;

    // ---- reduce across 32 k-slices: 4 DPP row-rotates + xor-16 swizzle ----
    DPP_ROR_ADD(accA, 0x128); DPP_ROR_ADD(accA, 0x124);
    DPP_ROR_ADD(accA, 0x122); DPP_ROR_ADD(accA, 0x121);
    accA += __int_as_float(__builtin_amdgcn_ds_swizzle(__float_as_int(accA), 0x401F));
    DPP_ROR_ADD(accB, 0x128); DPP_ROR_ADD(accB, 0x124);
    DPP_ROR_ADD(accB, 0x122); DPP_ROR_ADD(accB, 0x121);
    accB += __int_as_float(__builtin_amdgcn_ds_swizzle(__float_as_int(accB), 0x401F));

    if (s == 0){ zbuf[r0] = accA; zbuf[r1] = accB; }
    if (gloader){ gsh[gl]=pgi; gsh[16+gl]=pgf; gsh[32+gl]=pgg; gsh[48+gl]=pgo; }
    WAITLGKM(); SB0();
    __builtin_amdgcn_s_barrier(); SB0();   // raw barrier #2

    // ---- gate math + state update for this wg's 16 hidden units ----
    if (tid < 16){
      float zi = zbuf[tid]      + gsh[tid];
      float zf = zbuf[16 + tid] + gsh[16 + tid];
      float zg = zbuf[32 + tid] + gsh[32 + tid];
      float zo = zbuf[48 + tid] + gsh[48 + tid];
      float si = __builtin_amdgcn_rcpf(1.f + __expf(-zi));
      float sf = __builtin_amdgcn_rcpf(1.f + __expf(-zf));
      float so = __builtin_amdgcn_rcpf(1.f + __expf(-zo));
      float tg = 1.f - 2.f*__builtin_amdgcn_rcpf(__expf(2.f*zg) + 1.f);
      cst = sf*cst + si*tg;
      float tc = 1.f - 2.f*__builtin_amdgcn_rcpf(__expf(2.f*cst) + 1.f);
      float hv  = so*tc;
      uint32_t u = __float_as_uint(hv);
      if (u == POISON) hv = __uint_as_float(u ^ 1u);   // keep poison unambiguous

      st_ic(&hb[(size_t)(t+1)*HH + j0 + tid], hv);     // publish FIRST (coalesced)

      const int n = dir ? (t ^ 7) : t;                 // undo per-sample reversal
      out[(size_t)n*(2*HH) + dir*HH + j0 + tid] = hv;

      if (t == NSEQ-1){
        out[(size_t)NSEQ*2*HH + dir*HH + j0 + tid] = hv;          // h_n
        out[(size_t)NSEQ*2*HH + 2*HH + dir*HH + j0 + tid] = cst;  // c_n
      }
    }

    // ---- wave 0: issue next step's polls (after stores; asm order holds) ----
    if (wv == 0 && t < NSEQ-1){
      const float* hpn = &hb[(size_t)(t+1)*HH + (lane<<3)];
      poll_issue(hpn, pA0, pB0);
      __builtin_amdgcn_s_sleep(4);    // ~256cy stagger: samples land ~RTT/2 apart
      poll_issue(hpn, pA1, pB1);
    }
    // No trailing barrier: next-step hsh4 writes are gated behind barrier #1,
    // which requires the gate threads (wave 0) to have finished publishing.
  }
}

// ---------------------------------------------------------------------------
extern "C" void kernel_launch(void* const* d_in, const int* in_sizes, int n_in,
                              void* d_out, int out_size, void* d_ws, size_t ws_size,
                              hipStream_t stream)
{
  const float* x    = (const float*)d_in[0];
  const float* h0   = (const float*)d_in[1];
  const float* c0   = (const float*)d_in[2];
  const float* Wihf = (const float*)d_in[3];
  const float* Whhf = (const float*)d_in[4];
  const float* bf   = (const float*)d_in[5];
  const float* Wihb = (const float*)d_in[6];
  const float* Whhb = (const float*)d_in[7];
  const float* bb   = (const float*)d_in[8];
  float* out = (float*)d_out;
  float* ws  = (float*)d_ws;

  float* g    = ws;                 // [2][8192][2048] fp32
  float* hbuf = ws + G_ELEMS;       // [2][8193][512]  fp32

  {
    int total = (int)HB_ELEMS;
    int blocks = (total + 255) / 256;
    init_hbuf_k<<<blocks, 256, 0, stream>>>(hbuf, h0);
  }
  {
    dim3 grid(NSEQ/64, (2*FOURH)/64);   // (128, 64)
    gemm_ih_k<<<grid, 256, 0, stream>>>(x, Wihf, bf, Wihb, bb, g);
  }
  scan_k<<<64, 1024, 0, stream>>>(Whhf, Whhb, c0, g, hbuf, out);
}

// Round 7
// 11569.696 us; speedup vs baseline: 2.9597x; 1.2302x over previous
//
#include <hip/hip_runtime.h>
#include <stdint.h>

// Problem dims (fixed by the reference)
#define BSZ   1024
#define TT    8
#define DD    512
#define HH    512
#define NSEQ  (BSZ*TT)          // 8192 sequential steps per direction
#define FOURH (4*HH)            // 2048
#define POISON 0xAAAAAAAAu
#define G_ELEMS  ((size_t)2*NSEQ*FOURH)      // 33,554,432 floats (128 MB)
#define HB_ELEMS ((size_t)2*(NSEQ+1)*HH)     //  8,389,632 floats (32 MB)
#define POLL_CAP (1<<16)

typedef __attribute__((ext_vector_type(4))) float vf4;

// IC-coherent 32B load (bypasses L1+L2; serial wait — ROUND-0 PROVEN FORM).
__device__ __forceinline__ void ld2x16_ic(const float* p, vf4& a, vf4& b){
  asm volatile("global_load_dwordx4 %0, %2, off sc0 sc1\n\t"
               "global_load_dwordx4 %1, %2, off offset:16 sc0 sc1\n\t"
               "s_waitcnt vmcnt(0)"
               : "=v"(a), "=v"(b) : "v"(p) : "memory");
}
// IC-coherent 4B publish store.
__device__ __forceinline__ void st_ic(float* p, float v){
  asm volatile("global_store_dword %0, %1, off sc0 sc1"
               :: "v"(p), "v"(v) : "memory");
}

// ---------------------------------------------------------------------------
// Init: poison the h-pipeline buffer, seed slot 0 with h0 (LSB-flip if it
// happens to equal the poison bit pattern).
// ---------------------------------------------------------------------------
__global__ void init_hbuf_k(float* __restrict__ hbuf, const float* __restrict__ h0)
{
  size_t idx = (size_t)blockIdx.x*blockDim.x + threadIdx.x;
  if (idx >= HB_ELEMS) return;
  int j = (int)(idx % HH);
  size_t r = idx / HH;
  int t   = (int)(r % (NSEQ+1));
  int dir = (int)(r / (NSEQ+1));
  uint32_t v;
  if (t == 0){
    uint32_t u = __float_as_uint(h0[dir*HH + j]);
    if (u == POISON) u ^= 1u;
    v = u;
  } else {
    v = POISON;
  }
  ((uint32_t*)hbuf)[idx] = v;
}

// ---------------------------------------------------------------------------
// Input-side GEMM: g[dir][n][m] = x[row]·W_ih_dir[m] + b_dir[m]
//   dir 0: row = n ; dir 1: row = n^7  (per-sample time reversal, T=8)
// ---------------------------------------------------------------------------
__global__ __launch_bounds__(256) void gemm_ih_k(
    const float* __restrict__ x,
    const float* __restrict__ Wf, const float* __restrict__ bf,
    const float* __restrict__ Wb, const float* __restrict__ bb,
    float* __restrict__ g)
{
  const int bm = blockIdx.x;          // 128 row tiles
  const int bn = blockIdx.y;          // 64 col tiles over combined N=4096
  const int n0  = bm*64;
  const int m0g = bn*64;
  const int dir = m0g >> 11;          // /2048
  const int m0  = m0g & 2047;
  const float* __restrict__ W    = dir ? Wb : Wf;
  const float* __restrict__ bias = dir ? bb : bf;

  __shared__ float As[32][68];
  __shared__ float Bs[32][68];

  const int tid = threadIdx.x;
  const int tx = tid & 15, ty = tid >> 4;
  float acc[4][4] = {};

  const int lr = tid >> 2;            // 0..63
  const int lk = (tid & 3) * 8;       // 0,8,16,24
  int arow = n0 + lr; if (dir) arow ^= 7;
  const float* ap = &x[(size_t)arow*DD];
  const float* wp = &W[(size_t)(m0+lr)*DD];

  for (int k0 = 0; k0 < DD; k0 += 32){
    float4 a0 = *(const float4*)&ap[k0+lk];
    float4 a1 = *(const float4*)&ap[k0+lk+4];
    float4 w0 = *(const float4*)&wp[k0+lk];
    float4 w1 = *(const float4*)&wp[k0+lk+4];
    __syncthreads();
    As[lk+0][lr]=a0.x; As[lk+1][lr]=a0.y; As[lk+2][lr]=a0.z; As[lk+3][lr]=a0.w;
    As[lk+4][lr]=a1.x; As[lk+5][lr]=a1.y; As[lk+6][lr]=a1.z; As[lk+7][lr]=a1.w;
    Bs[lk+0][lr]=w0.x; Bs[lk+1][lr]=w0.y; Bs[lk+2][lr]=w0.z; Bs[lk+3][lr]=w0.w;
    Bs[lk+4][lr]=w1.x; Bs[lk+5][lr]=w1.y; Bs[lk+6][lr]=w1.z; Bs[lk+7][lr]=w1.w;
    __syncthreads();
    #pragma unroll
    for (int kk = 0; kk < 32; kk++){
      float4 av = *(const float4*)&As[kk][ty*4];
      float4 bv = *(const float4*)&Bs[kk][tx*4];
      acc[0][0]+=av.x*bv.x; acc[0][1]+=av.x*bv.y; acc[0][2]+=av.x*bv.z; acc[0][3]+=av.x*bv.w;
      acc[1][0]+=av.y*bv.x; acc[1][1]+=av.y*bv.y; acc[1][2]+=av.y*bv.z; acc[1][3]+=av.y*bv.w;
      acc[2][0]+=av.z*bv.x; acc[2][1]+=av.z*bv.y; acc[2][2]+=av.z*bv.z; acc[2][3]+=av.z*bv.w;
      acc[3][0]+=av.w*bv.x; acc[3][1]+=av.w*bv.y; acc[3][2]+=av.w*bv.z; acc[3][3]+=av.w*bv.w;
    }
  }

  const size_t gbase = (size_t)dir*NSEQ*FOURH;
  #pragma unroll
  for (int i = 0; i < 4; i++){
    const int n = n0 + ty*4 + i;
    #pragma unroll
    for (int j = 0; j < 4; j++){
      const int m = m0 + tx*4 + j;
      g[gbase + (size_t)n*FOURH + m] = acc[i][j] + bias[m];
    }
  }
}

// ---------------------------------------------------------------------------
// Sequential bidirectional scan — round-0 fabric VERBATIM (64 wgs, serial
// IC poll + s_sleep(1), __syncthreads barriers, gloader/zbuf, coalesced
// 16-lane publish) plus exactly the two independently-verified wins:
//  1. Strided column partition (r6-verified): lane k-slice s owns cols
//     {128q+4s+j}; linear LDS chunks; conflicts 1.34e8 -> 7.4e6.
//  2. rcp gate math (r6-verified numerics): removes 5 f32 divisions from the
//     serial publish chain. Plus publish-before-out ordering (free).
// ---------------------------------------------------------------------------
#define DPP_ROR_ADD(v, ctrl) do { \
    int _t = __builtin_amdgcn_update_dpp(0, __float_as_int(v), (ctrl), 0xf, 0xf, false); \
    (v) += __int_as_float(_t); } while (0)

__global__ __launch_bounds__(1024, 4) void scan_k(
    const float* __restrict__ Whh_f, const float* __restrict__ Whh_b,
    const float* __restrict__ c0, const float* __restrict__ g,
    float* __restrict__ hbuf, float* __restrict__ out)
{
  const int bx  = blockIdx.x;
  const int dir = bx >> 5;
  const int w   = bx & 31;
  const int j0  = w << 4;
  const int tid  = threadIdx.x;
  const int lane = tid & 63;
  const int wv   = tid >> 6;
  const int s    = lane & 31;         // k-slice id (32 slices x 16 strided cols)
  const int rb   = lane >> 5;
  const int r0   = (wv << 2) + rb;    // z-rows: wave wv covers rows 4wv..4wv+3
  const int r1   = r0 + 2;

  const float* __restrict__ Whh = dir ? Whh_b : Whh_f;

  __shared__ vf4  hsh4[128];          // h[t] broadcast, LINEAR chunks
  __shared__ float zbuf[64];
  __shared__ float gsh[64];
  __shared__ int dead;

  // Recurrent weights for rows r0/r1 over this lane's strided column set:
  // wX[4q+j] = W[row][128q + 4s + j]  (matches h4{a,b,c,d}[j] below).
  float wA[16], wB[16];
  {
    const int gA = r0 >> 4, hA = r0 & 15;
    const int gB = r1 >> 4, hB = r1 & 15;
    const float* pa = &Whh[(size_t)(gA*HH + j0 + hA)*HH];
    const float* pb = &Whh[(size_t)(gB*HH + j0 + hB)*HH];
    #pragma unroll
    for (int q = 0; q < 4; q++){
      float4 va = *(const float4*)&pa[q*128 + (s<<2)];
      wA[4*q+0]=va.x; wA[4*q+1]=va.y; wA[4*q+2]=va.z; wA[4*q+3]=va.w;
      float4 vb = *(const float4*)&pb[q*128 + (s<<2)];
      wB[4*q+0]=vb.x; wB[4*q+1]=vb.y; wB[4*q+2]=vb.z; wB[4*q+3]=vb.w;
    }
  }

  float cst = 0.f;
  if (tid < 16) cst = c0[dir*HH + j0 + tid];
  if (tid == 0) dead = 0;
  __syncthreads();

  float* __restrict__ hb = hbuf + (size_t)dir*(NSEQ+1)*HH;
  const float* __restrict__ gbp = g + (size_t)dir*NSEQ*FOURH;

  const bool gloader = (tid >= 64) && (tid < 80);
  const int  gl = tid - 64;

  for (int t = 0; t < NSEQ; t++){
    // g prefetch on wave 1 (off the polling wave's critical path).
    float pgi=0.f, pgf=0.f, pgg=0.f, pgo=0.f;
    if (gloader){
      const float* gp = &gbp[(size_t)t*FOURH + j0 + gl];
      pgi = gp[0]; pgf = gp[HH]; pgg = gp[2*HH]; pgo = gp[3*HH];
    }

    // Wave 0: poll h[t] (8 floats/lane) from IC until no poison remains.
    // ROUND-0 PROVEN serial form: issue+vmcnt(0)+check+sleep(1).
    if (wv == 0){
      const float* hp = &hb[(size_t)t*HH + (lane<<3)];
      vf4 a, b;
      int it = 0;
      for (;;){
        ld2x16_ic(hp, a, b);
        bool ok = (__float_as_uint(a.x)!=POISON) & (__float_as_uint(a.y)!=POISON)
                & (__float_as_uint(a.z)!=POISON) & (__float_as_uint(a.w)!=POISON)
                & (__float_as_uint(b.x)!=POISON) & (__float_as_uint(b.y)!=POISON)
                & (__float_as_uint(b.z)!=POISON) & (__float_as_uint(b.w)!=POISON);
        if (ok) break;
        if (++it > POLL_CAP){ dead = 1; break; }
        __builtin_amdgcn_s_sleep(1);
      }
      // Linear LDS broadcast: lane L -> chunks {2L, 2L+1}.
      const int c0i = lane << 1;
      hsh4[c0i]     = a;
      hsh4[c0i + 1] = b;
    }
    __syncthreads();
    if (dead) break;

    // ---- read this lane's strided h slice: chunks {s, 32+s, 64+s, 96+s} ----
    vf4 h4a = hsh4[s];
    vf4 h4b = hsh4[32 + s];
    vf4 h4c = hsh4[64 + s];
    vf4 h4d = hsh4[96 + s];

    // Two 16-long dot products per lane (4 independent FMA chains).
    float a0=0.f, a1=0.f, b0=0.f, b1=0.f;
    a0 += wA[ 0]*h4a.x; a1 += wA[ 1]*h4a.y; a0 += wA[ 2]*h4a.z; a1 += wA[ 3]*h4a.w;
    a0 += wA[ 4]*h4b.x; a1 += wA[ 5]*h4b.y; a0 += wA[ 6]*h4b.z; a1 += wA[ 7]*h4b.w;
    a0 += wA[ 8]*h4c.x; a1 += wA[ 9]*h4c.y; a0 += wA[10]*h4c.z; a1 += wA[11]*h4c.w;
    a0 += wA[12]*h4d.x; a1 += wA[13]*h4d.y; a0 += wA[14]*h4d.z; a1 += wA[15]*h4d.w;
    b0 += wB[ 0]*h4a.x; b1 += wB[ 1]*h4a.y; b0 += wB[ 2]*h4a.z; b1 += wB[ 3]*h4a.w;
    b0 += wB[ 4]*h4b.x; b1 += wB[ 5]*h4b.y; b0 += wB[ 6]*h4b.z; b1 += wB[ 7]*h4b.w;
    b0 += wB[ 8]*h4c.x; b1 += wB[ 9]*h4c.y; b0 += wB[10]*h4c.z; b1 += wB[11]*h4c.w;
    b0 += wB[12]*h4d.x; b1 += wB[13]*h4d.y; b0 += wB[14]*h4d.z; b1 += wB[15]*h4d.w;
    float accA = a0 + a1, accB = b0 + b1;

    // Reduce across 32 k-slices: 4 DPP row-rotates (within 16) + xor-16 swizzle.
    DPP_ROR_ADD(accA, 0x128); DPP_ROR_ADD(accA, 0x124);
    DPP_ROR_ADD(accA, 0x122); DPP_ROR_ADD(accA, 0x121);
    accA += __int_as_float(__builtin_amdgcn_ds_swizzle(__float_as_int(accA), 0x401F));
    DPP_ROR_ADD(accB, 0x128); DPP_ROR_ADD(accB, 0x124);
    DPP_ROR_ADD(accB, 0x122); DPP_ROR_ADD(accB, 0x121);
    accB += __int_as_float(__builtin_amdgcn_ds_swizzle(__float_as_int(accB), 0x401F));

    if (s == 0){ zbuf[r0] = accA; zbuf[r1] = accB; }
    if (gloader){ gsh[gl]=pgi; gsh[16+gl]=pgf; gsh[32+gl]=pgg; gsh[48+gl]=pgo; }
    __syncthreads();

    // Gate math + state update for this wg's 16 hidden units.
    if (tid < 16){
      float zi = zbuf[tid]      + gsh[tid];
      float zf = zbuf[16 + tid] + gsh[16 + tid];
      float zg = zbuf[32 + tid] + gsh[32 + tid];
      float zo = zbuf[48 + tid] + gsh[48 + tid];
      float si = __builtin_amdgcn_rcpf(1.f + __expf(-zi));
      float sf = __builtin_amdgcn_rcpf(1.f + __expf(-zf));
      float so = __builtin_amdgcn_rcpf(1.f + __expf(-zo));
      float tg = 1.f - 2.f*__builtin_amdgcn_rcpf(__expf(2.f*zg) + 1.f);
      cst = sf*cst + si*tg;
      float tc = 1.f - 2.f*__builtin_amdgcn_rcpf(__expf(2.f*cst) + 1.f);
      float hv  = so*tc;
      uint32_t u = __float_as_uint(hv);
      if (u == POISON) hv = __uint_as_float(u ^ 1u);   // keep poison unambiguous

      st_ic(&hb[(size_t)(t+1)*HH + j0 + tid], hv);     // publish FIRST (coalesced)

      const int n = dir ? (t ^ 7) : t;                 // undo per-sample reversal
      out[(size_t)n*(2*HH) + dir*HH + j0 + tid] = hv;

      if (t == NSEQ-1){
        out[(size_t)NSEQ*2*HH + dir*HH + j0 + tid] = hv;          // h_n
        out[(size_t)NSEQ*2*HH + 2*HH + dir*HH + j0 + tid] = cst;  // c_n
      }
    }
    // No trailing barrier: next-step hsh4/zbuf writes are gated behind the
    // barrier following wave 0's poll of h[t+1], which requires these gate
    // threads (in wave 0) to have finished publishing.
  }
}

// ---------------------------------------------------------------------------
extern "C" void kernel_launch(void* const* d_in, const int* in_sizes, int n_in,
                              void* d_out, int out_size, void* d_ws, size_t ws_size,
                              hipStream_t stream)
{
  const float* x    = (const float*)d_in[0];
  const float* h0   = (const float*)d_in[1];
  const float* c0   = (const float*)d_in[2];
  const float* Wihf = (const float*)d_in[3];
  const float* Whhf = (const float*)d_in[4];
  const float* bf   = (const float*)d_in[5];
  const float* Wihb = (const float*)d_in[6];
  const float* Whhb = (const float*)d_in[7];
  const float* bb   = (const float*)d_in[8];
  float* out = (float*)d_out;
  float* ws  = (float*)d_ws;

  float* g    = ws;                 // [2][8192][2048] fp32
  float* hbuf = ws + G_ELEMS;       // [2][8193][512]  fp32

  {
    int total = (int)HB_ELEMS;
    int blocks = (total + 255) / 256;
    init_hbuf_k<<<blocks, 256, 0, stream>>>(hbuf, h0);
  }
  {
    dim3 grid(NSEQ/64, (2*FOURH)/64);   // (128, 64)
    gemm_ih_k<<<grid, 256, 0, stream>>>(x, Wihf, bf, Wihb, bb, g);
  }
  scan_k<<<64, 1024, 0, stream>>>(Whhf, Whhb, c0, g, hbuf, out);
}